// Round 3
// baseline (360.124 us; speedup 1.0000x reference)
//
#include <hip/hip_runtime.h>
#include <hip/hip_bf16.h>
#include <cstdint>

typedef __bf16 bf16;
typedef __bf16 bf16_8 __attribute__((ext_vector_type(8)));
typedef __bf16 bf16_4 __attribute__((ext_vector_type(4)));
typedef float f32_4 __attribute__((ext_vector_type(4)));
typedef short s16x4 __attribute__((ext_vector_type(4)));
typedef short s16x8 __attribute__((ext_vector_type(8)));

#define MFMA_16x16x32(a, b, c) __builtin_amdgcn_mfma_f32_16x16x32_bf16((a), (b), (c), 0, 0, 0)

__device__ __forceinline__ void gll16(const void* g, void* l) {
  __builtin_amdgcn_global_load_lds((const __attribute__((address_space(1))) void*)g,
                                   (__attribute__((address_space(3))) void*)l, 16, 0, 0);
}

__device__ __forceinline__ float exp2fast(float x) {
#if __has_builtin(__builtin_amdgcn_exp2f)
  return __builtin_amdgcn_exp2f(x);
#else
  return __exp2f(x);
#endif
}

__device__ __forceinline__ unsigned bfbits(float x) {
  bf16 b = (bf16)x;
  return (unsigned)__builtin_bit_cast(unsigned short, b);
}

// ---------------- fp32 -> bf16 converters -----------------------------------
__global__ __launch_bounds__(256) void cvt3(const float* __restrict__ s0,
                                            const float* __restrict__ s1,
                                            const float* __restrict__ s2,
                                            bf16* __restrict__ d0,
                                            bf16* __restrict__ d1,
                                            bf16* __restrict__ d2) {
  const float* srcs[3] = {s0, s1, s2};
  bf16* dsts[3] = {d0, d1, d2};
  const float* src = srcs[blockIdx.y];
  bf16* dst = dsts[blockIdx.y];
  size_t i = ((size_t)blockIdx.x * 256 + threadIdx.x) * 8;
  float4 f0 = *(const float4*)(src + i);
  float4 f1 = *(const float4*)(src + i + 4);
  bf16_8 v;
  v[0] = (bf16)f0.x; v[1] = (bf16)f0.y; v[2] = (bf16)f0.z; v[3] = (bf16)f0.w;
  v[4] = (bf16)f1.x; v[5] = (bf16)f1.y; v[6] = (bf16)f1.z; v[7] = (bf16)f1.w;
  *(bf16_8*)(dst + i) = v;
}

// Wq (blockIdx.y==0) is PRE-SCALED by (1/sqrt(64))*log2(e) so attention scores
// arrive already in exp2-space: softmax becomes a bare v_exp per score.
// (bf16 rounding is scale-invariant; the fixed softmax bias C cancels in P/sum.)
__global__ __launch_bounds__(256) void convert4(const float* __restrict__ w0,
                                                const float* __restrict__ w1,
                                                const float* __restrict__ w2,
                                                const float* __restrict__ w3,
                                                bf16* __restrict__ out, int per) {
  const float* srcs[4] = {w0, w1, w2, w3};
  const float* src = srcs[blockIdx.y];
  bf16* dst = out + (size_t)blockIdx.y * per;
  const float sc = (blockIdx.y == 0) ? 0.18033688f : 1.0f;  // 0.125*log2(e)
  int i = (blockIdx.x * 256 + threadIdx.x) * 4;
  float4 f = *(const float4*)(src + i);
  bf16_4 v;
  v[0] = (bf16)(f.x * sc); v[1] = (bf16)(f.y * sc);
  v[2] = (bf16)(f.z * sc); v[3] = (bf16)(f.w * sc);
  *(bf16_4*)(dst + i) = v;
}

// ---------------- fused QKV projection GEMM ----------------------------------
// blockIdx.y in [0,24): tensor = y>>3 (0:q,1:k,2:v), n0 = (y&7)*128.
// Q/K written [token][E]; V written TRANSPOSED into Vt[(b*16+h)*64+d][s],
// with keys PAIR-PERMUTED within each 64-block:
//   k = t*16 + q*4 + j  ->  (t>>1)*32 + q*8 + (t&1)*4 + j
// This permuted order makes each b128 LDS read in attn's PV step a ready-made
// A-fragment of mfma_f32_16x16x32_bf16 (k-slot quad*8+j), whose matching
// B-fragment is just {pk[2i],pk[2i+1]} concatenated in registers.
__global__ __launch_bounds__(256) void gemm_qkv(const bf16* __restrict__ Aq,
                                                const bf16* __restrict__ Ak,
                                                const bf16* __restrict__ Av,
                                                const bf16* __restrict__ W,
                                                bf16* __restrict__ Qp,
                                                bf16* __restrict__ Kp,
                                                bf16* __restrict__ Vt) {
  constexpr int BM = 128, BK = 32, K = 1024, N = 1024, M_S = 2048;
  __shared__ alignas(16) bf16 As[2][BM * BK];
  __shared__ alignas(16) bf16 Bs[2][BM * BK];

  const int tid = threadIdx.x;
  const int wave = tid >> 6, lane = tid & 63;
  const int quad = lane >> 4, l15 = lane & 15;
  const int wm = (wave & 1) * 64, wn = (wave >> 1) * 64;
  const int tensor = blockIdx.y >> 3;
  const int n0 = (blockIdx.y & 7) * 128;
  const size_t m0 = (size_t)blockIdx.x * BM;

  const bf16* A = tensor == 0 ? Aq : (tensor == 1 ? Ak : Av);
  const bf16* Bt = W + ((size_t)tensor << 20);

  f32_4 acc[4][4] = {};

  const size_t g_laneoff = (size_t)(lane >> 2) * K + (lane & 3) * 8;
  const bf16* Ag = A + (m0 + wave * 32) * (size_t)K + g_laneoff;
  const bf16* Bg = Bt + ((size_t)n0 + wave * 32) * (size_t)K + g_laneoff;
  const int l_off = wave * 32 * BK + lane * 8;

  auto stage = [&](int b, int k0) {
    gll16(Ag + k0, &As[b][l_off]);
    gll16(Ag + 16 * (size_t)K + k0, &As[b][l_off + 16 * BK]);
    gll16(Bg + k0, &Bs[b][l_off]);
    gll16(Bg + 16 * (size_t)K + k0, &Bs[b][l_off + 16 * BK]);
  };

  stage(0, 0);
  int buf = 0;
  for (int k0 = 0; k0 < K; k0 += BK, buf ^= 1) {
    __syncthreads();
    if (k0 + BK < K) stage(buf ^ 1, k0 + BK);

    bf16_8 af[4], bfr[4];
#pragma unroll
    for (int mt = 0; mt < 4; ++mt)
      af[mt] = *(const bf16_8*)&As[buf][(wm + mt * 16 + l15) * BK + quad * 8];
#pragma unroll
    for (int nt = 0; nt < 4; ++nt)
      bfr[nt] = *(const bf16_8*)&Bs[buf][(wn + nt * 16 + l15) * BK + quad * 8];
#pragma unroll
    for (int mt = 0; mt < 4; ++mt)
#pragma unroll
      for (int nt = 0; nt < 4; ++nt)
        acc[mt][nt] = MFMA_16x16x32(af[mt], bfr[nt], acc[mt][nt]);
  }

  if (tensor < 2) {
    bf16* C = tensor == 0 ? Qp : Kp;
#pragma unroll
    for (int mt = 0; mt < 4; ++mt)
#pragma unroll
      for (int i = 0; i < 4; ++i) {
        size_t row = m0 + wm + mt * 16 + quad * 4 + i;
        bf16* cr = C + row * N + n0 + wn + l15;
#pragma unroll
        for (int nt = 0; nt < 4; ++nt) cr[nt * 16] = (bf16)acc[mt][nt][i];
      }
  } else {
    const int bb = (int)(m0 >> 11);
    const int sbase = (int)(m0 & 2047) + wm;
#pragma unroll
    for (int mt = 0; mt < 4; ++mt)
#pragma unroll
      for (int nt = 0; nt < 4; ++nt) {
        int col = n0 + wn + nt * 16 + l15;
        bf16_4 pk;
        pk[0] = (bf16)acc[mt][nt][0]; pk[1] = (bf16)acc[mt][nt][1];
        pk[2] = (bf16)acc[mt][nt][2]; pk[3] = (bf16)acc[mt][nt][3];
        // pair-permuted key index: mt*16+quad*4 -> (mt>>1)*32 + quad*8 + (mt&1)*4
        bf16* dst = Vt + ((size_t)(bb * 16 + (col >> 6)) * 64 + (col & 63)) * M_S +
                    sbase + (mt >> 1) * 32 + quad * 8 + (mt & 1) * 4;
        *(bf16_4*)dst = pk;
      }
  }
}

// ---------------- output projection GEMM (fp32 out) --------------------------
__global__ __launch_bounds__(256) void gemm_out(const bf16* __restrict__ A,
                                                const bf16* __restrict__ Bt,
                                                float* __restrict__ C,
                                                int M, int N, int K) {
  constexpr int BM = 128, BN = 128, BK = 32;
  __shared__ alignas(16) bf16 As[2][BM * BK];
  __shared__ alignas(16) bf16 Bs[2][BN * BK];

  const int tid = threadIdx.x;
  const int wave = tid >> 6, lane = tid & 63;
  const int quad = lane >> 4, l15 = lane & 15;
  const int wm = (wave & 1) * 64, wn = (wave >> 1) * 64;
  const size_t m0 = (size_t)blockIdx.x * BM;
  const size_t n0 = (size_t)blockIdx.y * BN;

  f32_4 acc[4][4] = {};

  const size_t g_laneoff = (size_t)(lane >> 2) * K + (lane & 3) * 8;
  const bf16* Ag = A + (m0 + wave * 32) * (size_t)K + g_laneoff;
  const bf16* Bg = Bt + (n0 + wave * 32) * (size_t)K + g_laneoff;
  const int l_off = wave * 32 * BK + lane * 8;

  auto stage = [&](int b, int k0) {
    gll16(Ag + k0, &As[b][l_off]);
    gll16(Ag + 16 * (size_t)K + k0, &As[b][l_off + 16 * BK]);
    gll16(Bg + k0, &Bs[b][l_off]);
    gll16(Bg + 16 * (size_t)K + k0, &Bs[b][l_off + 16 * BK]);
  };

  stage(0, 0);
  int buf = 0;
  for (int k0 = 0; k0 < K; k0 += BK, buf ^= 1) {
    __syncthreads();
    if (k0 + BK < K) stage(buf ^ 1, k0 + BK);

    bf16_8 af[4], bfr[4];
#pragma unroll
    for (int mt = 0; mt < 4; ++mt)
      af[mt] = *(const bf16_8*)&As[buf][(wm + mt * 16 + l15) * BK + quad * 8];
#pragma unroll
    for (int nt = 0; nt < 4; ++nt)
      bfr[nt] = *(const bf16_8*)&Bs[buf][(wn + nt * 16 + l15) * BK + quad * 8];
#pragma unroll
    for (int mt = 0; mt < 4; ++mt)
#pragma unroll
      for (int nt = 0; nt < 4; ++nt)
        acc[mt][nt] = MFMA_16x16x32(af[mt], bfr[nt], acc[mt][nt]);
  }

#pragma unroll
  for (int mt = 0; mt < 4; ++mt)
#pragma unroll
    for (int i = 0; i < 4; ++i) {
      size_t row = m0 + wm + mt * 16 + quad * 4 + i;
      float* cr = C + row * N + n0 + wn + l15;
#pragma unroll
      for (int nt = 0; nt < 4; ++nt) cr[nt * 16] = acc[mt][nt][i];
    }
}

// ---------------- fused flash attention, register-resident P -----------------
// 512 threads = 8 waves; each wave owns 16 q-rows (block = 128 q-rows of one
// (b,h)). K-tiles of 64, KV double-buffered in LDS. Per-wave state ~halved vs
// the 4-wave version -> <=64 VGPR -> 8 waves/SIMD (was 4): the QK->exp->PV
// dependency chain is latency-bound, so 2x resident waves is the lever.
// S^T = K.Q^T (Q pre-scaled in exp2-space by convert4) so softmax is a bare
// v_exp; exp(S^T) C-layout IS half a x32 B-frag; pair-permuted Vt makes each
// b128 V read the matching x32 A-frag. Denominator via ones-MFMA.
// XCD swizzle: all 16 q-tile blocks of one (b,h) share blockIdx.x%8 -> one
// XCD's L2 retains that head's K+V (512 KB).
__global__ __launch_bounds__(512, 8) void attn_fused(const bf16* __restrict__ Q,
                                                     const bf16* __restrict__ K,
                                                     const bf16* __restrict__ Vt,
                                                     const unsigned char* __restrict__ mask,
                                                     const float* __restrict__ gamma,
                                                     bf16* __restrict__ Out) {
  constexpr int S = 2048, E = 1024;
  constexpr float NEGB = -3.0e38f;                 // masked-key bias (exp2 -> 0)
  __shared__ alignas(16) bf16 Ks[2][64 * 64];
  __shared__ alignas(16) bf16 Vs[2][64 * 64];

  const int tid = threadIdx.x;
  const int wave = tid >> 6, lane = tid & 63;
  const int quad = lane >> 4, l15 = lane & 15;

  // XCD-grouping swizzle: hw XCD = (bx + 16*by)%8 = bx%8. For fixed work-bh,
  // blocks use bx in {wy&7, (wy&7)+8} -> constant bx%8 -> one XCD.
  const int bx = blockIdx.x, by = blockIdx.y;
  const int wx = (bx >> 3) | ((by & 7) << 1);      // q-tile index 0..15
  const int wy = (bx & 7) | (by & ~7);             // bh 0..63
  const int q0 = wx * 128;
  const int bh = wy;
  const int b = bh >> 4, h = bh & 15;

  const unsigned char* mg = mask + (size_t)b * S;

  // ---- per-wave "any key masked?" flag (2 loads + ballot; no LDS/barrier) ----
  bool anym;
  {
    const uint4* m4 = (const uint4*)mg;            // 64 lanes * 32B = 2048B = S
    uint4 x = m4[lane * 2], y = m4[lane * 2 + 1];
    unsigned o = (x.x | x.y | x.z | x.w) | (y.x | y.y | y.z | y.w);
    anym = __ballot(o != 0) != 0ull;
  }

  // staging lane offsets (8 chunks of 16B per 128B row, XOR swizzle by row&7)
  const int lrow = lane >> 3;                      // 0..7
  const int sx = ((lane & 7) ^ lrow) * 8;          // swizzled source chunk (elems)
  const size_t koff = (size_t)lrow * E + sx;       // K is [token][E]
  const size_t voff = (size_t)lrow * S + sx;       // Vt is [d][S]

  const bf16* Qg = Q + ((size_t)(b * S + q0)) * E + h * 64;
  const bf16* Kg = K + ((size_t)b * S) * E + h * 64;
  const bf16* Vg = Vt + ((size_t)bh * 64) * S;

  // each of the 8 waves stages 8 rows of K and 8 rows of V (1 gll16 each)
  auto stageKV = [&](int bf_, int kt) {
    gll16(Kg + (size_t)(kt + wave * 8) * E + koff, &Ks[bf_][wave * 8 * 64 + lane * 8]);
    gll16(Vg + (size_t)(wave * 8) * S + voff + kt, &Vs[bf_][wave * 8 * 64 + lane * 8]);
  };

  stageKV(0, 0);

  // ---- Q fragments: straight global->register ----
  bf16_8 qf[2];
#pragma unroll
  for (int ks = 0; ks < 2; ++ks)
    qf[ks] = *(const bf16_8*)(Qg + (size_t)(wave * 16 + l15) * E + ks * 32 + quad * 8);

  s16x8 onesP;
#pragma unroll
  for (int j = 0; j < 8; ++j) onesP[j] = (short)0x3F80;
  const bf16_8 onesA8 = __builtin_bit_cast(bf16_8, onesP);

  f32_4 accO[4] = {};   // [d-tile], O^T C-layout (col = query = l15)
  f32_4 accR = {};      // softmax denominator (ones^T . P^T), rows equal

  int buf = 0;
  for (int kt = 0; kt < S; kt += 64, buf ^= 1) {
    __syncthreads();                       // drains stage(cur) issued last iter
    if (kt + 64 < S) stageKV(buf ^ 1, kt + 64);

    s16x4 pk[4];
#pragma unroll
    for (int th = 0; th < 2; ++th) {       // t-pairs: caps live sT at 2 tiles
      f32_4 s0 = {}, s1 = {};
#pragma unroll
      for (int ks = 0; ks < 2; ++ks) {
        const int xo = ((ks * 4 + quad) ^ (l15 & 7)) * 8;
        bf16_8 a0 = *(const bf16_8*)&Ks[buf][((2 * th) * 16 + l15) * 64 + xo];
        bf16_8 a1 = *(const bf16_8*)&Ks[buf][((2 * th + 1) * 16 + l15) * 64 + xo];
        s0 = MFMA_16x16x32(a0, qf[ks], s0);
        s1 = MFMA_16x16x32(a1, qf[ks], s1);
      }
#pragma unroll
      for (int u = 0; u < 2; ++u) {
        const int t = 2 * th + u;
        const f32_4 sv = u ? s1 : s0;
        float e0, e1, e2, e3;
        if (anym) {
          const unsigned um = *(const unsigned*)(mg + kt + t * 16 + quad * 4);
          e0 = exp2fast(sv[0] + ((um & 0xffu) ? NEGB : 0.0f));
          e1 = exp2fast(sv[1] + ((um & 0xff00u) ? NEGB : 0.0f));
          e2 = exp2fast(sv[2] + ((um & 0xff0000u) ? NEGB : 0.0f));
          e3 = exp2fast(sv[3] + ((um & 0xff000000u) ? NEGB : 0.0f));
        } else {
          e0 = exp2fast(sv[0]); e1 = exp2fast(sv[1]);
          e2 = exp2fast(sv[2]); e3 = exp2fast(sv[3]);
        }
        uint2 uu;
        uu.x = bfbits(e0) | (bfbits(e1) << 16);
        uu.y = bfbits(e2) | (bfbits(e3) << 16);
        pk[t] = __builtin_bit_cast(s16x4, uu);
      }
    }

    // ---- O^T += V^T.P^T at full rate (x32): A = V^T b128 (LDS),
    //      B = {pk[2i],pk[2i+1]} register concat; denominator via ones-MFMA ----
#pragma unroll
    for (int i2 = 0; i2 < 2; ++i2) {
      const bf16_8 pb = __builtin_bit_cast(bf16_8,
          __builtin_shufflevector(pk[2 * i2], pk[2 * i2 + 1], 0, 1, 2, 3, 4, 5, 6, 7));
      accR = MFMA_16x16x32(onesA8, pb, accR);
      const int xo = ((i2 * 4 + quad) ^ (l15 & 7)) * 8;
#pragma unroll
      for (int dt = 0; dt < 4; ++dt) {
        bf16_8 vf = *(const bf16_8*)&Vs[buf][(dt * 16 + l15) * 64 + xo];
        accO[dt] = MFMA_16x16x32(vf, pb, accO[dt]);
      }
    }
  }

  // ---- finalize: accR holds full row-sum (K=32 spans all quads) ----
  const float invv = gamma[h] / accR[0];

  const size_t token = (size_t)(b * S) + q0 + wave * 16 + l15;
  bf16* orow = Out + token * E + h * 64;
#pragma unroll
  for (int dt = 0; dt < 4; ++dt) {
    bf16_4 ov;
    ov[0] = (bf16)(accO[dt][0] * invv);
    ov[1] = (bf16)(accO[dt][1] * invv);
    ov[2] = (bf16)(accO[dt][2] * invv);
    ov[3] = (bf16)(accO[dt][3] * invv);
    *(bf16_4*)(orow + dt * 16 + quad * 4) = ov;
  }
}

// ---------------- launch ------------------------------------------------------
extern "C" void kernel_launch(void* const* d_in, const int* in_sizes, int n_in,
                              void* d_out, int out_size, void* d_ws, size_t ws_size,
                              hipStream_t stream) {
  constexpr int Bb = 4, S = 2048, E = 1024;
  constexpr int M = Bb * S;  // 8192

  const float* q = (const float*)d_in[0];
  const float* k = (const float*)d_in[1];
  const float* v = (const float*)d_in[2];
  const unsigned char* mask = (const unsigned char*)d_in[3];
  const float* Wq = (const float*)d_in[4];
  const float* Wk = (const float*)d_in[5];
  const float* Wv = (const float*)d_in[6];
  const float* Wo = (const float*)d_in[7];
  const float* gamma = (const float*)d_in[8];

  // ws (72 MiB): Wb[0,8M) | qb[8,24M) (later At) | kb[24,40M) | vb[40,56M) | Vt[56,72M)
  // d_out (32 MiB fp32, fully overwritten by final GEMM) doubles as Qp+Kp scratch.
  char* ws = (char*)d_ws;
  bf16* Wb = (bf16*)ws;
  bf16* qb = (bf16*)(ws + ((size_t)8 << 20));
  bf16* kb = (bf16*)(ws + ((size_t)24 << 20));
  bf16* vb = (bf16*)(ws + ((size_t)40 << 20));
  bf16* Vt = (bf16*)(ws + ((size_t)56 << 20));
  bf16* Qp = (bf16*)d_out;
  bf16* Kp = (bf16*)d_out + ((size_t)1 << 23);  // +16 MiB

  convert4<<<dim3(1024, 4), 256, 0, stream>>>(Wq, Wk, Wv, Wo, Wb, 1 << 20);
  cvt3<<<dim3(4096, 3), 256, 0, stream>>>(q, k, v, qb, kb, vb);

  gemm_qkv<<<dim3(M / 128, 24), 256, 0, stream>>>(qb, kb, vb, Wb, Qp, Kp, Vt);

  bf16* At = qb;  // qb dead after gemm_qkv
  attn_fused<<<dim3(S / 128, Bb * 16), 512, 0, stream>>>(Qp, Kp, Vt, mask, gamma, At);

  gemm_out<<<dim3(M / 128, E / 128), 256, 0, stream>>>(At, Wb + (3 << 20), (float*)d_out, M, E, E);
}